// Round 1
// baseline (3365.768 us; speedup 1.0000x reference)
//
#include <hip/hip_runtime.h>

#define NN   40000
#define EE   640000
#define DIN  127
#define HH   128
#define NSEGS 512
#define SEGSZ 64

// ---------------- h0 = concat(x, batch_indicator) ----------------
__global__ void build_h0(const float* __restrict__ x, float* __restrict__ h) {
    int t = blockIdx.x * 256 + threadIdx.x;
    if (t >= NN * HH) return;
    int i = t >> 7, d = t & 127;
    h[t] = (d < DIN) ? x[i * DIN + d] : 0.f;
}

__global__ void set_bf(const int* __restrict__ batches, float* __restrict__ h) {
    int j = blockIdx.x * 256 + threadIdx.x;
    if (j < NSEGS * SEGSZ) h[batches[j] * HH + DIN] = 1.0f;
}

__global__ void copy4(const float4* __restrict__ src, float4* __restrict__ dst, int n4) {
    int t = blockIdx.x * 256 + threadIdx.x;
    if (t < n4) dst[t] = src[t];
}

// ---------------- edge scatter: acc[dst] += ew * h[src] ----------------
__global__ void edge_scatter(const float* __restrict__ h, const int* __restrict__ ei,
                             const float* __restrict__ ew, float* __restrict__ acc) {
    int t = blockIdx.x * 256 + threadIdx.x;
    if (t >= EE * 32) return;
    int e = t >> 5;
    int q = (t & 31) << 2;
    int s = ei[e], d = ei[EE + e];
    float w = ew[e];
    float4 v = *(const float4*)(h + s * HH + q);
    float* p = acc + d * HH + q;
    atomicAdd(p + 0, w * v.x);
    atomicAdd(p + 1, w * v.y);
    atomicAdd(p + 2, w * v.z);
    atomicAdd(p + 3, w * v.w);
}

// ---------------- hout = relu(tin @ w + b), [NN,128]@[128,128] ----------------
// block: 64 rows x 128 cols, 256 threads; per-thread 8x4 register tile.
__global__ __launch_bounds__(256) void gemm_relu(const float* __restrict__ tin,
                                                 const float* __restrict__ w,
                                                 const float* __restrict__ b,
                                                 float* __restrict__ hout) {
    __shared__ float lh[64 * 132];   // stride 132 floats: conflict-free b128 reads
    int row0 = blockIdx.x * 64;
    int tid = threadIdx.x;
    for (int idx = tid; idx < 64 * 32; idx += 256) {
        int r = idx >> 5, ch = (idx & 31) << 2;
        float4 v = *(const float4*)(tin + (row0 + r) * HH + ch);
        *(float4*)(&lh[r * 132 + ch]) = v;
    }
    __syncthreads();
    int tc = tid & 31;   // columns: c0 = 4*tc
    int tr = tid >> 5;   // rows: tr + 8j
    int c0 = tc << 2;
    float acc[8][4];
#pragma unroll
    for (int j = 0; j < 8; j++)
        for (int q = 0; q < 4; q++) acc[j][q] = 0.f;
    for (int k = 0; k < HH; k += 4) {
        float4 w0 = *(const float4*)(w + (k + 0) * HH + c0);
        float4 w1 = *(const float4*)(w + (k + 1) * HH + c0);
        float4 w2 = *(const float4*)(w + (k + 2) * HH + c0);
        float4 w3 = *(const float4*)(w + (k + 3) * HH + c0);
#pragma unroll
        for (int j = 0; j < 8; j++) {
            int r = tr + (j << 3);
            float4 hv = *(const float4*)(&lh[r * 132 + k]);
            acc[j][0] += hv.x * w0.x + hv.y * w1.x + hv.z * w2.x + hv.w * w3.x;
            acc[j][1] += hv.x * w0.y + hv.y * w1.y + hv.z * w2.y + hv.w * w3.y;
            acc[j][2] += hv.x * w0.z + hv.y * w1.z + hv.z * w2.z + hv.w * w3.z;
            acc[j][3] += hv.x * w0.w + hv.y * w1.w + hv.z * w2.w + hv.w * w3.w;
        }
    }
    float4 bv = *(const float4*)(b + c0);
#pragma unroll
    for (int j = 0; j < 8; j++) {
        int r = row0 + tr + (j << 3);
        float4 o;
        o.x = fmaxf(acc[j][0] + bv.x, 0.f);
        o.y = fmaxf(acc[j][1] + bv.y, 0.f);
        o.z = fmaxf(acc[j][2] + bv.z, 0.f);
        o.w = fmaxf(acc[j][3] + bv.w, 0.f);
        *(float4*)(hout + r * HH + c0) = o;
    }
}

// ---------------- multipool: mean/min/max over 64 gathered rows ----------------
__global__ __launch_bounds__(128) void pool(const float* __restrict__ h,
                                            const int* __restrict__ batches,
                                            float* __restrict__ z) {
    int s = blockIdx.x, c = threadIdx.x;
    float sum = 0.f, mn = INFINITY, mx = -INFINITY;
    for (int j = 0; j < SEGSZ; j++) {
        int idx = batches[s * SEGSZ + j];
        float v = h[idx * HH + c];
        sum += v;
        mn = fminf(mn, v);
        mx = fmaxf(mx, v);
    }
    z[s * 384 + c] = sum * (1.f / SEGSZ);
    z[s * 384 + 128 + c] = mn;
    z[s * 384 + 256 + c] = mx;
}

// ---------------- readout MLP (one block of 128 threads per segment) ----------------
__device__ __forceinline__ float block_sum(float v, float* red, int c) {
    red[c] = v;
    __syncthreads();
#pragma unroll
    for (int off = 64; off > 0; off >>= 1) {
        if (c < off) red[c] += red[c + off];
        __syncthreads();
    }
    float r = red[0];
    __syncthreads();
    return r;
}

__global__ __launch_bounds__(128) void readout(const float* __restrict__ z,
    const float* __restrict__ w1, const float* __restrict__ b1,
    const float* __restrict__ g1, const float* __restrict__ be1,
    const float* __restrict__ w2, const float* __restrict__ b2,
    const float* __restrict__ g2, const float* __restrict__ be2,
    const float* __restrict__ w3, const float* __restrict__ b3,
    float* __restrict__ out) {
    __shared__ float zr[384];
    __shared__ float red[128];
    __shared__ float v1[128];
    int s = blockIdx.x, c = threadIdx.x;
    for (int k = c; k < 384; k += 128) zr[k] = z[s * 384 + k];
    __syncthreads();

    float a = b1[c];
    for (int k = 0; k < 384; k++) a += zr[k] * w1[k * HH + c];
    a = fmaxf(a, 0.f);
    // LN1 (relu then LN)
    float m = block_sum(a, red, c) * (1.f / HH);
    float d = a - m;
    float var = block_sum(d * d, red, c) * (1.f / HH);
    float v = d * rsqrtf(var + 1e-5f) * g1[c] + be1[c];
    v1[c] = v;
    __syncthreads();

    float a2 = b2[c];
    for (int k = 0; k < HH; k++) a2 += v1[k] * w2[k * HH + c];
    // LN2 then relu
    float m2 = block_sum(a2, red, c) * (1.f / HH);
    float d2 = a2 - m2;
    float var2 = block_sum(d2 * d2, red, c) * (1.f / HH);
    float t2 = d2 * rsqrtf(var2 + 1e-5f) * g2[c] + be2[c];
    float z2 = fmaxf(t2, 0.f);

    float tot = block_sum(z2 * w3[c], red, c);
    if (c == 0) out[s] = tot + b3[0];
}

extern "C" void kernel_launch(void* const* d_in, const int* in_sizes, int n_in,
                              void* d_out, int out_size, void* d_ws, size_t ws_size,
                              hipStream_t stream) {
    const float* x        = (const float*)d_in[0];
    const int*   ei       = (const int*)d_in[1];
    const float* ew       = (const float*)d_in[2];
    const int*   batches  = (const int*)d_in[3];
    const float* gw[3]    = {(const float*)d_in[5], (const float*)d_in[7], (const float*)d_in[9]};
    const float* gb[3]    = {(const float*)d_in[6], (const float*)d_in[8], (const float*)d_in[10]};
    const float* r_w1 = (const float*)d_in[11]; const float* r_b1 = (const float*)d_in[12];
    const float* ln1g = (const float*)d_in[13]; const float* ln1b = (const float*)d_in[14];
    const float* r_w2 = (const float*)d_in[15]; const float* r_b2 = (const float*)d_in[16];
    const float* ln2g = (const float*)d_in[17]; const float* ln2b = (const float*)d_in[18];
    const float* r_w3 = (const float*)d_in[19]; const float* r_b3 = (const float*)d_in[20];
    float* out = (float*)d_out;

    float* h0 = (float*)d_ws;          // NN*HH
    float* h1 = h0 + (size_t)NN * HH;  // NN*HH
    float* tb = h1 + (size_t)NN * HH;  // NN*HH
    float* z  = tb + (size_t)NN * HH;  // NSEGS*384

    build_h0<<<(NN * HH + 255) / 256, 256, 0, stream>>>(x, h0);
    set_bf<<<(NSEGS * SEGSZ + 255) / 256, 256, 0, stream>>>(batches, h0);

    float* hin = h0;
    float* hout = h1;
    for (int l = 0; l < 3; l++) {
        copy4<<<(NN * HH / 4 + 255) / 256, 256, 0, stream>>>((const float4*)hin, (float4*)tb, NN * HH / 4);
        edge_scatter<<<(EE * 32 + 255) / 256, 256, 0, stream>>>(hin, ei, ew, tb);
        gemm_relu<<<NN / 64, 256, 0, stream>>>(tb, gw[l], gb[l], hout);
        float* tmp = hin; hin = hout; hout = tmp;
    }

    pool<<<NSEGS, 128, 0, stream>>>(hin, batches, z);
    readout<<<NSEGS, 128, 0, stream>>>(z, r_w1, r_b1, ln1g, ln1b,
                                       r_w2, r_b2, ln2g, ln2b, r_w3, r_b3, out);
}

// Round 2
// 494.416 us; speedup vs baseline: 6.8076x; 6.8076x over previous
//
#include <hip/hip_runtime.h>

#define NN   40000
#define EE   640000
#define DIN  127
#define HH   128
#define NSEGS 512
#define SEGSZ 64

// ---------------- h0 = concat(x, batch_indicator) ----------------
__global__ void build_h0(const float* __restrict__ x, float* __restrict__ h) {
    int t = blockIdx.x * 256 + threadIdx.x;
    if (t >= NN * HH) return;
    int i = t >> 7, d = t & 127;
    h[t] = (d < DIN) ? x[i * DIN + d] : 0.f;
}

__global__ void set_bf(const int* __restrict__ batches, float* __restrict__ h) {
    int j = blockIdx.x * 256 + threadIdx.x;
    if (j < NSEGS * SEGSZ) h[batches[j] * HH + DIN] = 1.0f;
}

// ---------------- CSR build (once; edges constant across layers) ----------------
__global__ void zero_int(int* __restrict__ p, int n) {
    int t = blockIdx.x * 256 + threadIdx.x;
    if (t < n) p[t] = 0;
}

__global__ void count_deg(const int* __restrict__ ei, int* __restrict__ deg) {
    int e = blockIdx.x * 256 + threadIdx.x;
    if (e < EE) atomicAdd(&deg[ei[EE + e]], 1);
}

// single block, 1024 threads; chunked exclusive scan of deg[0..NN) -> rowptr, fill
__global__ __launch_bounds__(1024) void scan_deg(const int* __restrict__ deg,
                                                 int* __restrict__ rowptr,
                                                 int* __restrict__ fill) {
    __shared__ int part[1024];
    const int CK = (NN + 1023) / 1024;  // 40
    int t = threadIdx.x;
    int beg = t * CK;
    int s = 0;
    for (int i = 0; i < CK; i++) {
        int idx = beg + i;
        if (idx < NN) s += deg[idx];
    }
    part[t] = s;
    __syncthreads();
    for (int off = 1; off < 1024; off <<= 1) {
        int x = (t >= off) ? part[t - off] : 0;
        __syncthreads();
        part[t] += x;
        __syncthreads();
    }
    int run = (t == 0) ? 0 : part[t - 1];
    for (int i = 0; i < CK; i++) {
        int idx = beg + i;
        if (idx < NN) {
            int dv = deg[idx];
            rowptr[idx] = run;
            fill[idx] = run;
            run += dv;
        }
    }
    if (t == 1023) rowptr[NN] = part[1023];
}

__global__ void fill_csr(const int* __restrict__ ei, const float* __restrict__ ew,
                         int* __restrict__ fill, int* __restrict__ csr_src,
                         float* __restrict__ csr_w) {
    int e = blockIdx.x * 256 + threadIdx.x;
    if (e < EE) {
        int d = ei[EE + e];
        int pos = atomicAdd(&fill[d], 1);
        csr_src[pos] = ei[e];
        csr_w[pos] = ew[e];
    }
}

// ---------------- aggregation: out[n] = h[n] + sum_{e in CSR[n]} w_e * h[src_e] ----------------
// one wave (64 lanes) per node; lane owns columns [2*lane, 2*lane+1]
__global__ __launch_bounds__(256) void gin_agg(const float* __restrict__ h,
                                               const int* __restrict__ rowptr,
                                               const int* __restrict__ csr_src,
                                               const float* __restrict__ csr_w,
                                               float* __restrict__ outb) {
    int node = blockIdx.x * 4 + (threadIdx.x >> 6);
    if (node >= NN) return;
    int lane = threadIdx.x & 63;
    int c = lane << 1;
    int beg = rowptr[node], end = rowptr[node + 1];
    float2 acc = *(const float2*)(h + (size_t)node * HH + c);  // self term
    for (int p = beg; p < end; ++p) {
        int s = csr_src[p];
        float w = csr_w[p];
        float2 v = *(const float2*)(h + (size_t)s * HH + c);
        acc.x += w * v.x;
        acc.y += w * v.y;
    }
    *(float2*)(outb + (size_t)node * HH + c) = acc;
}

// ---------------- hout = relu(tin @ w + b), [NN,128]@[128,128] ----------------
__global__ __launch_bounds__(256) void gemm_relu(const float* __restrict__ tin,
                                                 const float* __restrict__ w,
                                                 const float* __restrict__ b,
                                                 float* __restrict__ hout) {
    __shared__ float lh[64 * 132];
    int row0 = blockIdx.x * 64;
    int tid = threadIdx.x;
    for (int idx = tid; idx < 64 * 32; idx += 256) {
        int r = idx >> 5, ch = (idx & 31) << 2;
        float4 v = *(const float4*)(tin + (row0 + r) * HH + ch);
        *(float4*)(&lh[r * 132 + ch]) = v;
    }
    __syncthreads();
    int tc = tid & 31;
    int tr = tid >> 5;
    int c0 = tc << 2;
    float acc[8][4];
#pragma unroll
    for (int j = 0; j < 8; j++)
        for (int q = 0; q < 4; q++) acc[j][q] = 0.f;
    for (int k = 0; k < HH; k += 4) {
        float4 w0 = *(const float4*)(w + (k + 0) * HH + c0);
        float4 w1 = *(const float4*)(w + (k + 1) * HH + c0);
        float4 w2 = *(const float4*)(w + (k + 2) * HH + c0);
        float4 w3 = *(const float4*)(w + (k + 3) * HH + c0);
#pragma unroll
        for (int j = 0; j < 8; j++) {
            int r = tr + (j << 3);
            float4 hv = *(const float4*)(&lh[r * 132 + k]);
            acc[j][0] += hv.x * w0.x + hv.y * w1.x + hv.z * w2.x + hv.w * w3.x;
            acc[j][1] += hv.x * w0.y + hv.y * w1.y + hv.z * w2.y + hv.w * w3.y;
            acc[j][2] += hv.x * w0.z + hv.y * w1.z + hv.z * w2.z + hv.w * w3.z;
            acc[j][3] += hv.x * w0.w + hv.y * w1.w + hv.z * w2.w + hv.w * w3.w;
        }
    }
    float4 bv = *(const float4*)(b + c0);
#pragma unroll
    for (int j = 0; j < 8; j++) {
        int r = row0 + tr + (j << 3);
        float4 o;
        o.x = fmaxf(acc[j][0] + bv.x, 0.f);
        o.y = fmaxf(acc[j][1] + bv.y, 0.f);
        o.z = fmaxf(acc[j][2] + bv.z, 0.f);
        o.w = fmaxf(acc[j][3] + bv.w, 0.f);
        *(float4*)(hout + r * HH + c0) = o;
    }
}

// ---------------- multipool ----------------
__global__ __launch_bounds__(128) void pool(const float* __restrict__ h,
                                            const int* __restrict__ batches,
                                            float* __restrict__ z) {
    int s = blockIdx.x, c = threadIdx.x;
    float sum = 0.f, mn = INFINITY, mx = -INFINITY;
    for (int j = 0; j < SEGSZ; j++) {
        int idx = batches[s * SEGSZ + j];
        float v = h[idx * HH + c];
        sum += v;
        mn = fminf(mn, v);
        mx = fmaxf(mx, v);
    }
    z[s * 384 + c] = sum * (1.f / SEGSZ);
    z[s * 384 + 128 + c] = mn;
    z[s * 384 + 256 + c] = mx;
}

// ---------------- readout MLP ----------------
__device__ __forceinline__ float block_sum(float v, float* red, int c) {
    red[c] = v;
    __syncthreads();
#pragma unroll
    for (int off = 64; off > 0; off >>= 1) {
        if (c < off) red[c] += red[c + off];
        __syncthreads();
    }
    float r = red[0];
    __syncthreads();
    return r;
}

__global__ __launch_bounds__(128) void readout(const float* __restrict__ z,
    const float* __restrict__ w1, const float* __restrict__ b1,
    const float* __restrict__ g1, const float* __restrict__ be1,
    const float* __restrict__ w2, const float* __restrict__ b2,
    const float* __restrict__ g2, const float* __restrict__ be2,
    const float* __restrict__ w3, const float* __restrict__ b3,
    float* __restrict__ out) {
    __shared__ float zr[384];
    __shared__ float red[128];
    __shared__ float v1[128];
    int s = blockIdx.x, c = threadIdx.x;
    for (int k = c; k < 384; k += 128) zr[k] = z[s * 384 + k];
    __syncthreads();

    float a = b1[c];
    for (int k = 0; k < 384; k++) a += zr[k] * w1[k * HH + c];
    a = fmaxf(a, 0.f);
    float m = block_sum(a, red, c) * (1.f / HH);
    float d = a - m;
    float var = block_sum(d * d, red, c) * (1.f / HH);
    float v = d * rsqrtf(var + 1e-5f) * g1[c] + be1[c];
    v1[c] = v;
    __syncthreads();

    float a2 = b2[c];
    for (int k = 0; k < HH; k++) a2 += v1[k] * w2[k * HH + c];
    float m2 = block_sum(a2, red, c) * (1.f / HH);
    float d2 = a2 - m2;
    float var2 = block_sum(d2 * d2, red, c) * (1.f / HH);
    float t2 = d2 * rsqrtf(var2 + 1e-5f) * g2[c] + be2[c];
    float z2 = fmaxf(t2, 0.f);

    float tot = block_sum(z2 * w3[c], red, c);
    if (c == 0) out[s] = tot + b3[0];
}

extern "C" void kernel_launch(void* const* d_in, const int* in_sizes, int n_in,
                              void* d_out, int out_size, void* d_ws, size_t ws_size,
                              hipStream_t stream) {
    const float* x        = (const float*)d_in[0];
    const int*   ei       = (const int*)d_in[1];
    const float* ew       = (const float*)d_in[2];
    const int*   batches  = (const int*)d_in[3];
    const float* gw[3]    = {(const float*)d_in[5], (const float*)d_in[7], (const float*)d_in[9]};
    const float* gb[3]    = {(const float*)d_in[6], (const float*)d_in[8], (const float*)d_in[10]};
    const float* r_w1 = (const float*)d_in[11]; const float* r_b1 = (const float*)d_in[12];
    const float* ln1g = (const float*)d_in[13]; const float* ln1b = (const float*)d_in[14];
    const float* r_w2 = (const float*)d_in[15]; const float* r_b2 = (const float*)d_in[16];
    const float* ln2g = (const float*)d_in[17]; const float* ln2b = (const float*)d_in[18];
    const float* r_w3 = (const float*)d_in[19]; const float* r_b3 = (const float*)d_in[20];
    float* out = (float*)d_out;

    // workspace layout
    float* h0    = (float*)d_ws;            // NN*HH
    float* h1    = h0 + (size_t)NN * HH;    // NN*HH
    float* tb    = h1 + (size_t)NN * HH;    // NN*HH
    float* z     = tb + (size_t)NN * HH;    // NSEGS*384
    float* csr_w = z + (size_t)NSEGS * 384; // EE
    int* rowptr  = (int*)(csr_w + EE);      // NN+1
    int* deg     = rowptr + (NN + 1);       // NN
    int* fill    = deg + NN;                // NN
    int* csr_src = fill + NN;               // EE

    // CSR build (edges identical for all 3 layers)
    zero_int<<<(NN + 255) / 256, 256, 0, stream>>>(deg, NN);
    count_deg<<<(EE + 255) / 256, 256, 0, stream>>>(ei, deg);
    scan_deg<<<1, 1024, 0, stream>>>(deg, rowptr, fill);
    fill_csr<<<(EE + 255) / 256, 256, 0, stream>>>(ei, ew, fill, csr_src, csr_w);

    build_h0<<<(NN * HH + 255) / 256, 256, 0, stream>>>(x, h0);
    set_bf<<<(NSEGS * SEGSZ + 255) / 256, 256, 0, stream>>>(batches, h0);

    float* hin = h0;
    float* hout = h1;
    for (int l = 0; l < 3; l++) {
        gin_agg<<<(NN + 3) / 4, 256, 0, stream>>>(hin, rowptr, csr_src, csr_w, tb);
        gemm_relu<<<NN / 64, 256, 0, stream>>>(tb, gw[l], gb[l], hout);
        float* tmp = hin; hin = hout; hout = tmp;
    }

    pool<<<NSEGS, 128, 0, stream>>>(hin, batches, z);
    readout<<<NSEGS, 128, 0, stream>>>(z, r_w1, r_b1, ln1g, ln1b,
                                       r_w2, r_b2, ln2g, ln2b, r_w3, r_b3, out);
}